// Round 10
// baseline (125.908 us; speedup 1.0000x reference)
//
#include <hip/hip_runtime.h>
#include <hip/hip_bf16.h>
#include <math.h>

// ImplicitPolygonInjector: B=4, C=128, H=W=64, S=4
// out[b][j][h*4+sy][w*4+sx] = (relu(hf[b,h,w,:]+hg[sy,sx,:]+b1) @ w2 + b2)[j] * gate[b,h,w]
//
// R9 = R8 minus the hid LDS roundtrip: phase B builds the MFMA A-fragment
// (hidden) directly in registers from read-only hf_s/hgb_s. Steady state has
// ZERO LDS writes and ZERO barriers -- stores, LDS reads, VALU, MFMA mix freely
// across 16 waves/CU. hgb k-slice hoisted per quarter (32 regs, reused 4x mt).
// Store pattern identical to R8 (float4, compile-time offsets). Hidden values
// bit-identical to R8 (same bf16 cvt, no roundtrip) -> absmax should match.

typedef __attribute__((ext_vector_type(8))) short bf16x8;
typedef __attribute__((ext_vector_type(4))) float f32x4;

__device__ inline short f2bf(float v) {
    __hip_bfloat16 b = __float2bfloat16(v);
    return *reinterpret_cast<short*>(&b);
}

__device__ inline void barrier_lgkm() {
    asm volatile("s_waitcnt lgkmcnt(0)" ::: "memory");
    __builtin_amdgcn_s_barrier();
    asm volatile("" ::: "memory");
}

// ---------------- pre-kernel: transposes + bf16 hi/lo split ----------------
__global__ __launch_bounds__(256) void ipi_pre_kernel(
    const float* __restrict__ w2,    // (128,128)
    const float* __restrict__ w1,    // (130,128) -- rows 0..127 used
    const float* __restrict__ gw1,   // (128,32)
    __hip_bfloat16* __restrict__ w2t,     // (128j,128k)
    __hip_bfloat16* __restrict__ w1t_hi,  // (128j,128c)
    __hip_bfloat16* __restrict__ w1t_lo,
    __hip_bfloat16* __restrict__ g1t_hi,  // (32jg,128c)
    __hip_bfloat16* __restrict__ g1t_lo)
{
    int gid = blockIdx.x * 256 + threadIdx.x;
    if (gid < 16384) {
        int j = gid >> 7, k = gid & 127;
        w2t[gid] = __float2bfloat16(w2[k * 128 + j]);
    } else if (gid < 32768) {
        int i = gid - 16384, j = i >> 7, c = i & 127;
        float v = w1[c * 128 + j];
        __hip_bfloat16 hi = __float2bfloat16(v);
        w1t_hi[i] = hi;
        w1t_lo[i] = __float2bfloat16(v - __bfloat162float(hi));
    } else if (gid < 36864) {
        int i = gid - 32768, jg = i >> 7, c = i & 127;
        float v = gw1[c * 32 + jg];
        __hip_bfloat16 hi = __float2bfloat16(v);
        g1t_hi[i] = hi;
        g1t_lo[i] = __float2bfloat16(v - __bfloat162float(hi));
    }
}

// ---------------- main kernel ----------------
__global__ __launch_bounds__(256, 4) void ipi_main(
    const float* __restrict__ feat,     // (4,128,64,64)
    const float* __restrict__ mlp_w1,   // (130,128) -- rows 128,129 (grid coords)
    const float* __restrict__ mlp_b1,   // (128,)
    const float* __restrict__ gate_w2,  // (32,)
    const float* __restrict__ gate_b2,  // (1,)
    const float* __restrict__ mlp_b2,   // (128,)
    const __hip_bfloat16* __restrict__ w2t,
    const __hip_bfloat16* __restrict__ w1t_hi,
    const __hip_bfloat16* __restrict__ w1t_lo,
    const __hip_bfloat16* __restrict__ g1t_hi,
    const __hip_bfloat16* __restrict__ g1t_lo,
    float* __restrict__ out)            // (4,128,256,256)
{
    __shared__ float hf_s[16 * 132];    // hf[w][k] fp32 (read-only after prologue)
    __shared__ float hgb_s[16 * 132];   // hgb[s][k] fp32 (read-only after prologue)
    __shared__ float gate_s[16];
    __shared__ short f_hi[16 * 136];    // prologue only
    __shared__ short f_lo[16 * 136];
    __shared__ float glds[16 * 33];     // prologue only

    const int t    = threadIdx.x;
    const int lane = t & 63;
    const int lg   = lane >> 4;         // 0..3 (k-group / D-row group)
    const int ml   = lane & 15;         // A-row within tile / j within tile
    const int wv   = t >> 6;            // wave id -> j-range wv*32..+31
    const int bx   = blockIdx.x;
    const int w0   = (bx & 3) * 16;
    const int h    = (bx >> 2) & 63;
    const int b    = bx >> 8;

    // ---- w2t fragments (B-operand: col j = ml, k = lg*8+ks*32) + b2 splat ----
    bf16x8 wfrag[2][4];
    f32x4  b2s[2];
    {
        const __hip_bfloat16* base = w2t + (wv * 32 + ml) * 128 + lg * 8;
        #pragma unroll
        for (int jt = 0; jt < 2; ++jt) {
            #pragma unroll
            for (int ks = 0; ks < 4; ++ks)
                wfrag[jt][ks] = *(const bf16x8*)(base + jt * 2048 + ks * 32);
            float bj = mlp_b2[wv * 32 + jt * 16 + ml];
            b2s[jt] = (f32x4){bj, bj, bj, bj};
        }
    }

    // store base: plane j = wv*32 + jt*16 + ml; x = w0*4 + mt*16 + lg*4 (+r)
    float* pq = out + ((size_t)(b * 128 + wv * 32 + ml) << 16)
                    + (size_t)(h * 4) * 256 + w0 * 4 + lg * 4;

    // ---- stage f (transposed, bf16 hi/lo) + hgb ----
    {
        const float* fbase = feat + ((size_t)(b * 128) * 64 + h) * 64 + w0;
        #pragma unroll
        for (int i = 0; i < 8; ++i) {
            int idx = t + i * 256;            // 2048 = 128c * 16w
            int c = idx >> 4, w = idx & 15;
            float v = fbase[(size_t)c * 4096 + w];
            short hi = f2bf(v);
            float hf32 = __bfloat162float(*(__hip_bfloat16*)&hi);
            f_hi[w * 136 + c] = hi;
            f_lo[w * 136 + c] = f2bf(v - hf32);
        }
        #pragma unroll
        for (int i = 0; i < 8; ++i) {
            int idx = t + i * 256;            // 2048 = 16s * 128k
            int s = idx >> 7, k = idx & 127;
            float cx = -0.75f + 0.5f * (float)(s & 3);
            float cy = -0.75f + 0.5f * (float)(s >> 2);
            hgb_s[s * 132 + k] = cx * mlp_w1[16384 + k]
                               + cy * mlp_w1[16512 + k] + mlp_b1[k];
        }
    }
    barrier_lgkm();

    // ---- hf = f @ w1_f via split-bf16 MFMA (all waves); gate MFMA (wave 0) ----
    {
        bf16x8 fhi[4], flo[4];
        {
            const short* fb  = f_hi + ml * 136 + lg * 8;
            const short* flb = f_lo + ml * 136 + lg * 8;
            #pragma unroll
            for (int ks = 0; ks < 4; ++ks) {
                fhi[ks] = *(const bf16x8*)(fb + ks * 32);
                flo[ks] = *(const bf16x8*)(flb + ks * 32);
            }
        }
        #pragma unroll
        for (int jj = 0; jj < 2; ++jj) {
            const int jt16 = (wv * 2 + jj) * 16;
            const __hip_bfloat16* bh = w1t_hi + (jt16 + ml) * 128 + lg * 8;
            const __hip_bfloat16* bl = w1t_lo + (jt16 + ml) * 128 + lg * 8;
            f32x4 acc = {0.f, 0.f, 0.f, 0.f};
            #pragma unroll
            for (int ks = 0; ks < 4; ++ks) {
                bf16x8 Bh = *(const bf16x8*)(bh + ks * 32);
                bf16x8 Bl = *(const bf16x8*)(bl + ks * 32);
                acc = __builtin_amdgcn_mfma_f32_16x16x32_bf16(fhi[ks], Bh, acc, 0, 0, 0);
                acc = __builtin_amdgcn_mfma_f32_16x16x32_bf16(fhi[ks], Bl, acc, 0, 0, 0);
                acc = __builtin_amdgcn_mfma_f32_16x16x32_bf16(flo[ks], Bh, acc, 0, 0, 0);
            }
            #pragma unroll
            for (int r = 0; r < 4; ++r)
                hf_s[(lg * 4 + r) * 132 + jt16 + ml] = acc[r];
        }
        if (wv == 0) {
            #pragma unroll
            for (int jt = 0; jt < 2; ++jt) {
                const __hip_bfloat16* bh = g1t_hi + (jt * 16 + ml) * 128 + lg * 8;
                const __hip_bfloat16* bl = g1t_lo + (jt * 16 + ml) * 128 + lg * 8;
                f32x4 acc = {0.f, 0.f, 0.f, 0.f};
                #pragma unroll
                for (int ks = 0; ks < 4; ++ks) {
                    bf16x8 Bh = *(const bf16x8*)(bh + ks * 32);
                    bf16x8 Bl = *(const bf16x8*)(bl + ks * 32);
                    acc = __builtin_amdgcn_mfma_f32_16x16x32_bf16(fhi[ks], Bh, acc, 0, 0, 0);
                    acc = __builtin_amdgcn_mfma_f32_16x16x32_bf16(fhi[ks], Bl, acc, 0, 0, 0);
                    acc = __builtin_amdgcn_mfma_f32_16x16x32_bf16(flo[ks], Bh, acc, 0, 0, 0);
                }
                #pragma unroll
                for (int r = 0; r < 4; ++r) {
                    float v = acc[r];
                    glds[(lg * 4 + r) * 33 + jt * 16 + ml] = (v >= 0.f) ? v : 0.2f * v;
                }
            }
        }
    }
    barrier_lgkm();

    // ---- gate = sigmoid(g @ gate_w2 + b2) ----
    if (t < 16) {
        float s = gate_b2[0];
        #pragma unroll 8
        for (int jg = 0; jg < 32; ++jg) s = fmaf(glds[t * 33 + jg], gate_w2[jg], s);
        gate_s[t] = 1.f / (1.f + expf(-s));
    }
    barrier_lgkm();   // LAST barrier; LDS is read-only below

    // ---- steady state: 4 quarters x 4 m-tiles, NO barriers, NO LDS writes ----
    const int sx   = ml & 3;            // A-row m = mt*16+ml -> sx = ml&3
    const int wrow = ml >> 2;           // w = mt*4 + wrow (A-side)
    float gq[4];                        // gate for D rows: w = mt*4 + lg
    #pragma unroll
    for (int mt = 0; mt < 4; ++mt) gq[mt] = gate_s[mt * 4 + lg];

    #pragma unroll 1
    for (int q = 0; q < 4; ++q) {
        // hoist hgb slice for this quarter: row q*4+sx, k = lg*8 + ks*32 (+0..7)
        const float* hgr = hgb_s + (q * 4 + sx) * 132 + lg * 8;
        float4 hg0[4], hg1[4];
        #pragma unroll
        for (int ks = 0; ks < 4; ++ks) {
            hg0[ks] = *(const float4*)(hgr + ks * 32);
            hg1[ks] = *(const float4*)(hgr + ks * 32 + 4);
        }

        #pragma unroll
        for (int mt = 0; mt < 4; ++mt) {
            const float* hfr = hf_s + (mt * 4 + wrow) * 132 + lg * 8;
            f32x4 acc0 = b2s[0];
            f32x4 acc1 = b2s[1];
            #pragma unroll
            for (int ks = 0; ks < 4; ++ks) {
                float4 a0 = *(const float4*)(hfr + ks * 32);
                float4 a1 = *(const float4*)(hfr + ks * 32 + 4);
                bf16x8 bf;
                bf[0] = f2bf(fmaxf(a0.x + hg0[ks].x, 0.f));
                bf[1] = f2bf(fmaxf(a0.y + hg0[ks].y, 0.f));
                bf[2] = f2bf(fmaxf(a0.z + hg0[ks].z, 0.f));
                bf[3] = f2bf(fmaxf(a0.w + hg0[ks].w, 0.f));
                bf[4] = f2bf(fmaxf(a1.x + hg1[ks].x, 0.f));
                bf[5] = f2bf(fmaxf(a1.y + hg1[ks].y, 0.f));
                bf[6] = f2bf(fmaxf(a1.z + hg1[ks].z, 0.f));
                bf[7] = f2bf(fmaxf(a1.w + hg1[ks].w, 0.f));
                acc0 = __builtin_amdgcn_mfma_f32_16x16x32_bf16(bf, wfrag[0][ks], acc0, 0, 0, 0);
                acc1 = __builtin_amdgcn_mfma_f32_16x16x32_bf16(bf, wfrag[1][ks], acc1, 0, 0, 0);
            }

            const float g = gq[mt];
            float4 o;
            o.x = acc0[0] * g; o.y = acc0[1] * g;
            o.z = acc0[2] * g; o.w = acc0[3] * g;
            *(float4*)(pq + q * 256 + mt * 16) = o;
            o.x = acc1[0] * g; o.y = acc1[1] * g;
            o.z = acc1[2] * g; o.w = acc1[3] * g;
            *(float4*)(pq + ((size_t)16 << 16) + q * 256 + mt * 16) = o;
        }
    }
}

extern "C" void kernel_launch(void* const* d_in, const int* in_sizes, int n_in,
                              void* d_out, int out_size, void* d_ws, size_t ws_size,
                              hipStream_t stream) {
    const float* feat = (const float*)d_in[0];
    const float* gw1  = (const float*)d_in[1];
    const float* gw2  = (const float*)d_in[2];
    const float* gb2  = (const float*)d_in[3];
    const float* w1   = (const float*)d_in[4];
    const float* b1   = (const float*)d_in[5];
    const float* w2   = (const float*)d_in[6];
    const float* b2   = (const float*)d_in[7];
    float* o = (float*)d_out;

    // ws: w2t 32K | w1t_hi 32K | w1t_lo 32K | g1t_hi 8K | g1t_lo 8K = 112K
    char* ws = (char*)d_ws;
    __hip_bfloat16* w2t    = (__hip_bfloat16*)(ws);
    __hip_bfloat16* w1t_hi = (__hip_bfloat16*)(ws + 32768);
    __hip_bfloat16* w1t_lo = (__hip_bfloat16*)(ws + 65536);
    __hip_bfloat16* g1t_hi = (__hip_bfloat16*)(ws + 98304);
    __hip_bfloat16* g1t_lo = (__hip_bfloat16*)(ws + 106496);

    ipi_pre_kernel<<<dim3(144), dim3(256), 0, stream>>>(
        w2, w1, gw1, w2t, w1t_hi, w1t_lo, g1t_hi, g1t_lo);
    ipi_main<<<dim3(1024), dim3(256), 0, stream>>>(
        feat, w1, b1, gw2, gb2, b2, w2t, w1t_hi, w1t_lo, g1t_hi, g1t_lo, o);
}

// Round 11
// 46.023 us; speedup vs baseline: 2.7357x; 2.7357x over previous
//
#include <hip/hip_runtime.h>
#include <hip/hip_bf16.h>
#include <math.h>

// ImplicitPolygonInjector: B=4, C=128, H=W=64, S=4
// out[b][j][h*4+sy][w*4+sx] = (relu(hf[b,h,w,:]+hg[sy,sx,:]+b1) @ w2 + b2)[j] * gate[b,h,w]
//
// R10 = R8 skeleton with phase B switched to mfma_f32_32x32x16_bf16, D[j][m]:
// D col = lane&31 = m = x -> each scalar store instruction writes 2 FULL 128B
// lines (32 contiguous x across lanes 0-31 / 32-63 on two j-planes). This
// tests the half-line write-efficiency theory (R8 stores were 64B segments;
// effective write BW was ~3.2TB/s vs fill's 6.6TB/s).
// Prologue, phase A, barriers, LDS identical to R8. lgkm-only barriers.

typedef __attribute__((ext_vector_type(8))) short bf16x8;
typedef __attribute__((ext_vector_type(4))) float f32x4;
typedef __attribute__((ext_vector_type(16))) float f32x16;

__device__ inline short f2bf(float v) {
    __hip_bfloat16 b = __float2bfloat16(v);
    return *reinterpret_cast<short*>(&b);
}

__device__ inline void barrier_lgkm() {
    asm volatile("s_waitcnt lgkmcnt(0)" ::: "memory");
    __builtin_amdgcn_s_barrier();
    asm volatile("" ::: "memory");
}

// ---------------- pre-kernel: transposes + bf16 hi/lo split ----------------
__global__ __launch_bounds__(256) void ipi_pre_kernel(
    const float* __restrict__ w2,    // (128,128)
    const float* __restrict__ w1,    // (130,128) -- rows 0..127 used
    const float* __restrict__ gw1,   // (128,32)
    __hip_bfloat16* __restrict__ w2t,     // (128j,128k)
    __hip_bfloat16* __restrict__ w1t_hi,  // (128j,128c)
    __hip_bfloat16* __restrict__ w1t_lo,
    __hip_bfloat16* __restrict__ g1t_hi,  // (32jg,128c)
    __hip_bfloat16* __restrict__ g1t_lo)
{
    int gid = blockIdx.x * 256 + threadIdx.x;
    if (gid < 16384) {
        int j = gid >> 7, k = gid & 127;
        w2t[gid] = __float2bfloat16(w2[k * 128 + j]);
    } else if (gid < 32768) {
        int i = gid - 16384, j = i >> 7, c = i & 127;
        float v = w1[c * 128 + j];
        __hip_bfloat16 hi = __float2bfloat16(v);
        w1t_hi[i] = hi;
        w1t_lo[i] = __float2bfloat16(v - __bfloat162float(hi));
    } else if (gid < 36864) {
        int i = gid - 32768, jg = i >> 7, c = i & 127;
        float v = gw1[c * 32 + jg];
        __hip_bfloat16 hi = __float2bfloat16(v);
        g1t_hi[i] = hi;
        g1t_lo[i] = __float2bfloat16(v - __bfloat162float(hi));
    }
}

// ---------------- main kernel ----------------
__global__ __launch_bounds__(256, 4) void ipi_main(
    const float* __restrict__ feat,     // (4,128,64,64)
    const float* __restrict__ mlp_w1,   // (130,128) -- rows 128,129 (grid coords)
    const float* __restrict__ mlp_b1,   // (128,)
    const float* __restrict__ gate_w2,  // (32,)
    const float* __restrict__ gate_b2,  // (1,)
    const float* __restrict__ mlp_b2,   // (128,)
    const __hip_bfloat16* __restrict__ w2t,
    const __hip_bfloat16* __restrict__ w1t_hi,
    const __hip_bfloat16* __restrict__ w1t_lo,
    const __hip_bfloat16* __restrict__ g1t_hi,
    const __hip_bfloat16* __restrict__ g1t_lo,
    float* __restrict__ out)            // (4,128,256,256)
{
    __shared__ float hf_s[16 * 132];    // hf[w][k] fp32
    __shared__ float hgb_s[16 * 132];   // hgb[s][k] fp32
    __shared__ float gate_s[16];
    __shared__ char  hid[16384];        // bf16 [64 m][128 k], XOR-swizzled
    short* f_hi = (short*)hid;          // [16 w][136 c]  (prologue only)
    short* f_lo = (short*)(hid + 4352);
    float* glds = (float*)(hid + 8704); // [16 w][33 jg]  (dead after sigmoid)

    const int t    = threadIdx.x;
    const int lane = t & 63;
    const int lg   = lane >> 4;         // 0..3 (16x16 prologue roles)
    const int ml   = lane & 15;
    const int l32  = lane & 31;         // 32x32 roles
    const int lh   = lane >> 5;         // 0/1
    const int wv   = t >> 6;            // wave id -> j-range wv*32..+31
    const int bx   = blockIdx.x;
    const int w0   = (bx & 3) * 16;
    const int h    = (bx >> 2) & 63;
    const int b    = bx >> 8;

    // ---- w2t A-fragments for 32x32x16: row j = wv*32+l32, k = lh*8 + ks*16 ----
    bf16x8 wfrag[8];
    {
        const __hip_bfloat16* base = w2t + (wv * 32 + l32) * 128 + lh * 8;
        #pragma unroll
        for (int ks = 0; ks < 8; ++ks)
            wfrag[ks] = *(const bf16x8*)(base + ks * 16);
    }
    // ---- b2 per D-reg: j(r) = wv*32 + (r&3) + 8*(r>>2) + 4*lh ----
    float b2v[16];
    #pragma unroll
    for (int r = 0; r < 16; ++r)
        b2v[r] = mlp_b2[wv * 32 + (r & 3) + 8 * (r >> 2) + 4 * lh];

    // store base: plane j = wv*32 + 4*lh (+joff(r)), x = w0*4 + mt*32 + l32
    float* pq = out + ((size_t)(b * 128 + wv * 32 + 4 * lh) << 16)
                    + (size_t)(h * 4) * 256 + w0 * 4 + l32;

    // ---- stage f (transposed, bf16 hi/lo) + hgb ----
    {
        const float* fbase = feat + ((size_t)(b * 128) * 64 + h) * 64 + w0;
        #pragma unroll
        for (int i = 0; i < 8; ++i) {
            int idx = t + i * 256;            // 2048 = 128c * 16w
            int c = idx >> 4, w = idx & 15;
            float v = fbase[(size_t)c * 4096 + w];
            short hi = f2bf(v);
            float hf32 = __bfloat162float(*(__hip_bfloat16*)&hi);
            f_hi[w * 136 + c] = hi;
            f_lo[w * 136 + c] = f2bf(v - hf32);
        }
        #pragma unroll
        for (int i = 0; i < 8; ++i) {
            int idx = t + i * 256;            // 2048 = 16s * 128k
            int s = idx >> 7, k = idx & 127;
            float cx = -0.75f + 0.5f * (float)(s & 3);
            float cy = -0.75f + 0.5f * (float)(s >> 2);
            hgb_s[s * 132 + k] = cx * mlp_w1[16384 + k]
                               + cy * mlp_w1[16512 + k] + mlp_b1[k];
        }
    }
    barrier_lgkm();

    // ---- hf = f @ w1_f via split-bf16 16x16 MFMA (all waves); gate (wave 0) ----
    {
        bf16x8 fhi[4], flo[4];
        {
            const short* fb  = f_hi + ml * 136 + lg * 8;
            const short* flb = f_lo + ml * 136 + lg * 8;
            #pragma unroll
            for (int ks = 0; ks < 4; ++ks) {
                fhi[ks] = *(const bf16x8*)(fb + ks * 32);
                flo[ks] = *(const bf16x8*)(flb + ks * 32);
            }
        }
        #pragma unroll
        for (int jj = 0; jj < 2; ++jj) {
            const int jt16 = (wv * 2 + jj) * 16;
            const __hip_bfloat16* bh = w1t_hi + (jt16 + ml) * 128 + lg * 8;
            const __hip_bfloat16* bl = w1t_lo + (jt16 + ml) * 128 + lg * 8;
            f32x4 acc = {0.f, 0.f, 0.f, 0.f};
            #pragma unroll
            for (int ks = 0; ks < 4; ++ks) {
                bf16x8 Bh = *(const bf16x8*)(bh + ks * 32);
                bf16x8 Bl = *(const bf16x8*)(bl + ks * 32);
                acc = __builtin_amdgcn_mfma_f32_16x16x32_bf16(fhi[ks], Bh, acc, 0, 0, 0);
                acc = __builtin_amdgcn_mfma_f32_16x16x32_bf16(fhi[ks], Bl, acc, 0, 0, 0);
                acc = __builtin_amdgcn_mfma_f32_16x16x32_bf16(flo[ks], Bh, acc, 0, 0, 0);
            }
            #pragma unroll
            for (int r = 0; r < 4; ++r)
                hf_s[(lg * 4 + r) * 132 + jt16 + ml] = acc[r];
        }
        if (wv == 0) {
            #pragma unroll
            for (int jt = 0; jt < 2; ++jt) {
                const __hip_bfloat16* bh = g1t_hi + (jt * 16 + ml) * 128 + lg * 8;
                const __hip_bfloat16* bl = g1t_lo + (jt * 16 + ml) * 128 + lg * 8;
                f32x4 acc = {0.f, 0.f, 0.f, 0.f};
                #pragma unroll
                for (int ks = 0; ks < 4; ++ks) {
                    bf16x8 Bh = *(const bf16x8*)(bh + ks * 32);
                    bf16x8 Bl = *(const bf16x8*)(bl + ks * 32);
                    acc = __builtin_amdgcn_mfma_f32_16x16x32_bf16(fhi[ks], Bh, acc, 0, 0, 0);
                    acc = __builtin_amdgcn_mfma_f32_16x16x32_bf16(fhi[ks], Bl, acc, 0, 0, 0);
                    acc = __builtin_amdgcn_mfma_f32_16x16x32_bf16(flo[ks], Bh, acc, 0, 0, 0);
                }
                #pragma unroll
                for (int r = 0; r < 4; ++r) {
                    float v = acc[r];
                    glds[(lg * 4 + r) * 33 + jt * 16 + ml] = (v >= 0.f) ? v : 0.2f * v;
                }
            }
        }
    }
    barrier_lgkm();

    // ---- gate = sigmoid(g @ gate_w2 + b2) ----
    if (t < 16) {
        float s = gate_b2[0];
        #pragma unroll 8
        for (int jg = 0; jg < 32; ++jg) s = fmaf(glds[t * 33 + jg], gate_w2[jg], s);
        gate_s[t] = 1.f / (1.f + expf(-s));
    }
    barrier_lgkm();

    // ---- steady state: 4 quarters; {A; bar; B(32x32)+line stores; bar} ----
    for (int q = 0; q < 4; ++q) {
        // phase A: hid[m][k] = bf16(relu(hf[w][k] + hgb[q*4+sx][k])), 64 m rows
        {
            const int m0 = t >> 2;                    // 0..63
            const int w  = m0 >> 2;
            const int s  = (q << 2) | (m0 & 3);
            const float* hfr = hf_s  + w * 132 + (t & 3) * 32;
            const float* hgr = hgb_s + s * 132 + (t & 3) * 32;
            char* wp = hid + m0 * 256;
            const int sw = (m0 & 7) << 4;
            const int kb = (t & 3) * 64;
            #pragma unroll
            for (int kc = 0; kc < 4; ++kc) {
                float4 a0 = *(const float4*)(hfr + kc * 8);
                float4 a1 = *(const float4*)(hfr + kc * 8 + 4);
                float4 g0 = *(const float4*)(hgr + kc * 8);
                float4 g1 = *(const float4*)(hgr + kc * 8 + 4);
                bf16x8 hv;
                hv[0] = f2bf(fmaxf(a0.x + g0.x, 0.f));
                hv[1] = f2bf(fmaxf(a0.y + g0.y, 0.f));
                hv[2] = f2bf(fmaxf(a0.z + g0.z, 0.f));
                hv[3] = f2bf(fmaxf(a0.w + g0.w, 0.f));
                hv[4] = f2bf(fmaxf(a1.x + g1.x, 0.f));
                hv[5] = f2bf(fmaxf(a1.y + g1.y, 0.f));
                hv[6] = f2bf(fmaxf(a1.z + g1.z, 0.f));
                hv[7] = f2bf(fmaxf(a1.w + g1.w, 0.f));
                *(bf16x8*)(wp + ((kb + kc * 16) ^ sw)) = hv;
            }
        }
        barrier_lgkm();

        // phase B: per wave, 2 m-tiles of D[32 j][32 m] via 32x32x16 MFMA
        #pragma unroll
        for (int mt = 0; mt < 2; ++mt) {
            const int m  = mt * 32 + l32;            // B col = m row of hid
            const char* rp = hid + m * 256;
            const int swb = (m & 7) << 4;
            bf16x8 hfrag[8];
            #pragma unroll
            for (int ks = 0; ks < 8; ++ks)
                hfrag[ks] = *(const bf16x8*)(rp + ((ks * 32 + lh * 16) ^ swb));

            f32x16 acc;
            #pragma unroll
            for (int r = 0; r < 16; ++r) acc[r] = b2v[r];
            #pragma unroll
            for (int ks = 0; ks < 8; ++ks)
                acc = __builtin_amdgcn_mfma_f32_32x32x16_bf16(wfrag[ks], hfrag[ks], acc, 0, 0, 0);

            const float g = gate_s[mt * 8 + (l32 >> 2)];   // w = x>>2
            float* op = pq + q * 256 + mt * 32;
            #pragma unroll
            for (int r = 0; r < 16; ++r) {
                const size_t joff = (size_t)((r & 3) + 8 * (r >> 2)) << 16;
                op[joff] = acc[r] * g;
            }
        }
        barrier_lgkm();
    }
}

extern "C" void kernel_launch(void* const* d_in, const int* in_sizes, int n_in,
                              void* d_out, int out_size, void* d_ws, size_t ws_size,
                              hipStream_t stream) {
    const float* feat = (const float*)d_in[0];
    const float* gw1  = (const float*)d_in[1];
    const float* gw2  = (const float*)d_in[2];
    const float* gb2  = (const float*)d_in[3];
    const float* w1   = (const float*)d_in[4];
    const float* b1   = (const float*)d_in[5];
    const float* w2   = (const float*)d_in[6];
    const float* b2   = (const float*)d_in[7];
    float* o = (float*)d_out;

    // ws: w2t 32K | w1t_hi 32K | w1t_lo 32K | g1t_hi 8K | g1t_lo 8K = 112K
    char* ws = (char*)d_ws;
    __hip_bfloat16* w2t    = (__hip_bfloat16*)(ws);
    __hip_bfloat16* w1t_hi = (__hip_bfloat16*)(ws + 32768);
    __hip_bfloat16* w1t_lo = (__hip_bfloat16*)(ws + 65536);
    __hip_bfloat16* g1t_hi = (__hip_bfloat16*)(ws + 98304);
    __hip_bfloat16* g1t_lo = (__hip_bfloat16*)(ws + 106496);

    ipi_pre_kernel<<<dim3(144), dim3(256), 0, stream>>>(
        w2, w1, gw1, w2t, w1t_hi, w1t_lo, g1t_hi, g1t_lo);
    ipi_main<<<dim3(1024), dim3(256), 0, stream>>>(
        feat, w1, b1, gw2, gb2, b2, w2t, w1t_hi, w1t_lo, g1t_hi, g1t_lo, o);
}